// Round 5
// baseline (926.469 us; speedup 1.0000x reference)
//
#include <hip/hip_runtime.h>
#include <float.h>
#include <math.h>

// B=2, L=2048, DIM=DIM_ATTN=1024, 16 heads x 64
typedef short s16x8 __attribute__((ext_vector_type(8)));
typedef float f32x4 __attribute__((ext_vector_type(4)));
typedef unsigned short u16t;
typedef u16t u16x4v __attribute__((ext_vector_type(4)));

__device__ __forceinline__ u16t f2bf(float f){
  unsigned u = __builtin_bit_cast(unsigned, f);
  return (u16t)((u + 0x7FFFu + ((u >> 16) & 1u)) >> 16);   // RNE; inputs always finite/small
}
__device__ __forceinline__ float bf2f(u16t b){
  unsigned u = ((unsigned)b) << 16;
  return __builtin_bit_cast(float, u);
}
__device__ __forceinline__ f32x4 mfma16(s16x8 a, s16x8 b, f32x4 c){
  return __builtin_amdgcn_mfma_f32_16x16x32_bf16(a, b, c, 0, 0, 0);
}

// ---------------- prep: split fp32 -> bf16 hi/lo -----------------------------
__global__ __launch_bounds__(256) void prep_split(const float* __restrict__ X,
    u16t* __restrict__ H, u16t* __restrict__ L, int n8){
  int i = blockIdx.x * 256 + threadIdx.x;
  if (i >= n8) return;
  const float* p = X + (size_t)i * 8;
  float4 a = *(const float4*)p;
  float4 b = *(const float4*)(p + 4);
  float v[8] = {a.x, a.y, a.z, a.w, b.x, b.y, b.z, b.w};
  s16x8 hv, lv;
#pragma unroll
  for (int r = 0; r < 8; ++r){
    u16t hh = f2bf(v[r]);
    hv[r] = (short)hh;
    lv[r] = (short)f2bf(v[r] - bf2f(hh));
  }
  *(s16x8*)(H + (size_t)i * 8) = hv;
  *(s16x8*)(L + (size_t)i * 8) = lv;
}

// ---------------- prep: transpose weights [K][N]->[N][K] + split -------------
__global__ __launch_bounds__(256) void prep_wt(
    const float* __restrict__ Wq, const float* __restrict__ Wk,
    const float* __restrict__ Wv, const float* __restrict__ Wo,
    u16t* __restrict__ Qh, u16t* __restrict__ Ql,
    u16t* __restrict__ Kh, u16t* __restrict__ Kl,
    u16t* __restrict__ Vh,
    u16t* __restrict__ Oh, u16t* __restrict__ Ol){
  __shared__ float T[64][65];
  int z = blockIdx.z;
  const float* W = (z==0)?Wq:(z==1)?Wk:(z==2)?Wv:Wo;
  u16t* OH = (z==0)?Qh:(z==1)?Kh:(z==2)?Vh:Oh;
  u16t* OL = (z==0)?Ql:(z==1)?Kl:(z==2)?(u16t*)0:Ol;
  int k0 = blockIdx.x*64, n0 = blockIdx.y*64;
  int r = threadIdx.x >> 2, c = (threadIdx.x & 3) * 16;
#pragma unroll
  for (int i = 0; i < 4; ++i){
    float4 v = *(const float4*)&W[(size_t)(k0 + r)*1024 + n0 + c + i*4];
    T[r][c + i*4 + 0] = v.x; T[r][c + i*4 + 1] = v.y;
    T[r][c + i*4 + 2] = v.z; T[r][c + i*4 + 3] = v.w;
  }
  __syncthreads();
  // out[n][k] = W[k][n]; this thread: n = n0+r, k = k0+c .. +15
  s16x8 hv0, hv1, lv0, lv1;
#pragma unroll
  for (int i = 0; i < 16; ++i){
    float v = T[c + i][r];
    u16t hh = f2bf(v);
    u16t ll = f2bf(v - bf2f(hh));
    if (i < 8){ hv0[i] = (short)hh; lv0[i] = (short)ll; }
    else      { hv1[i-8] = (short)hh; lv1[i-8] = (short)ll; }
  }
  size_t o = (size_t)(n0 + r)*1024 + k0 + c;
  *(s16x8*)(OH + o)     = hv0;
  *(s16x8*)(OH + o + 8) = hv1;
  if (OL){ *(s16x8*)(OL + o) = lv0; *(s16x8*)(OL + o + 8) = lv1; }
}

// ---------------- MFMA GEMM: C[4096,1024] = A[4096,1024] @ B^T-layout --------
// A row-major bf16 (hi/lo), B given TRANSPOSED [N][K] bf16 (hi/lo).
// NSPLIT=3: acc += AhBh + AhBl + AlBh (fp32-quality). NSPLIT=1: plain bf16.
// MODE 0: bf16 hi/lo row-major out (Q/K). MODE 1: bf16 V^T[n][token] packed.
// MODE 2: fp32 row-major out.
template<int NSPLIT, int MODE>
__global__ __launch_bounds__(256) void gemm_k(
    const u16t* __restrict__ Agh, const u16t* __restrict__ Agl,
    const u16t* __restrict__ Bgh0, const u16t* __restrict__ Bgl0,
    const u16t* __restrict__ Bgh1, const u16t* __restrict__ Bgl1,
    u16t* __restrict__ Oh0, u16t* __restrict__ Ol0,
    u16t* __restrict__ Oh1, u16t* __restrict__ Ol1,
    float* __restrict__ Of)
{
  constexpr int NPLANES = (NSPLIT==3) ? 4 : 2;
  __shared__ u16t SM[NPLANES * 4096];          // planes of [128 rows][32 k] bf16
  u16t* AH = SM;
  u16t* AL = SM + 4096;                        // valid only when NSPLIT==3
  u16t* BH = SM + ((NSPLIT==3) ? 8192 : 4096);
  u16t* BL = SM + 12288;                       // valid only when NSPLIT==3

  const u16t* Bgh = blockIdx.z ? Bgh1 : Bgh0;
  const u16t* Bgl = blockIdx.z ? Bgl1 : Bgl0;
  u16t* Oh = blockIdx.z ? Oh1 : Oh0;
  u16t* Ol = blockIdx.z ? Ol1 : Ol0;

  const int t = threadIdx.x;
  const int lane = t & 63;
  const int wid = t >> 6;
  const int wm = wid >> 1, wn = wid & 1;       // 2x2 waves, 64x64 each
  const int bm = blockIdx.x * 128, bn = blockIdx.y * 128;
  const int li = lane & 15, lg = lane >> 4;

  f32x4 acc[4][4];
#pragma unroll
  for (int i = 0; i < 4; ++i)
#pragma unroll
    for (int j = 0; j < 4; ++j) acc[i][j] = f32x4{0.f, 0.f, 0.f, 0.f};

  for (int k0 = 0; k0 < 1024; k0 += 32){
    __syncthreads();
#pragma unroll
    for (int i = 0; i < 2; ++i){
      int cch = i*256 + t;                     // 512 chunks = 128 rows x 4 slots
      int row = cch >> 2, sl = cch & 3;
      int sw = (sl ^ ((row >> 1) & 3)) * 8;    // XOR swizzle (16B slots)
      *(s16x8*)&AH[row*32 + sw] = *(const s16x8*)&Agh[(size_t)(bm+row)*1024 + k0 + sl*8];
      if constexpr (NSPLIT == 3)
        *(s16x8*)&AL[row*32 + sw] = *(const s16x8*)&Agl[(size_t)(bm+row)*1024 + k0 + sl*8];
      *(s16x8*)&BH[row*32 + sw] = *(const s16x8*)&Bgh[(size_t)(bn+row)*1024 + k0 + sl*8];
      if constexpr (NSPLIT == 3)
        *(s16x8*)&BL[row*32 + sw] = *(const s16x8*)&Bgl[(size_t)(bn+row)*1024 + k0 + sl*8];
    }
    __syncthreads();

    s16x8 ah[4], alv[4], bh[4], blv[4];
#pragma unroll
    for (int i = 0; i < 4; ++i){
      int rowA = wm*64 + i*16 + li;
      int swA = (lg ^ ((rowA >> 1) & 3)) * 8;
      ah[i] = *(const s16x8*)&AH[rowA*32 + swA];
      if constexpr (NSPLIT == 3) alv[i] = *(const s16x8*)&AL[rowA*32 + swA];
      int rowB = wn*64 + i*16 + li;
      int swB = (lg ^ ((rowB >> 1) & 3)) * 8;
      bh[i] = *(const s16x8*)&BH[rowB*32 + swB];
      if constexpr (NSPLIT == 3) blv[i] = *(const s16x8*)&BL[rowB*32 + swB];
    }
#pragma unroll
    for (int i = 0; i < 4; ++i)
#pragma unroll
      for (int j = 0; j < 4; ++j){
        acc[i][j] = mfma16(ah[i], bh[j], acc[i][j]);
        if constexpr (NSPLIT == 3){
          acc[i][j] = mfma16(ah[i], blv[j], acc[i][j]);
          acc[i][j] = mfma16(alv[i], bh[j], acc[i][j]);
        }
      }
  }

  // epilogue: C/D frag = D[(lg*4+r)][li] per 16x16 tile (m89-verified layout)
#pragma unroll
  for (int i = 0; i < 4; ++i)
#pragma unroll
    for (int j = 0; j < 4; ++j){
      if constexpr (MODE == 1){
        int n = bn + wn*64 + j*16 + li;
        int tok0 = bm + wm*64 + i*16 + lg*4;
        u16x4v pk;
#pragma unroll
        for (int r = 0; r < 4; ++r) pk[r] = f2bf(acc[i][j][r]);
        *(u16x4v*)&Oh[(size_t)n*4096 + tok0] = pk;   // V^T[n][token], 4 tokens packed
      } else {
#pragma unroll
        for (int r = 0; r < 4; ++r){
          int tok = bm + wm*64 + i*16 + lg*4 + r;
          int col = bn + wn*64 + j*16 + li;
          float v = acc[i][j][r];
          if constexpr (MODE == 0){
            u16t hh = f2bf(v);
            Oh[(size_t)tok*1024 + col] = hh;
            Ol[(size_t)tok*1024 + col] = f2bf(v - bf2f(hh));
          } else {
            Of[(size_t)tok*1024 + col] = v;
          }
        }
      }
    }
}

// ---------------- MFMA flash attention, barrier-free -------------------------
// Block = (64-q-tile, head); 4 waves, each owns 16 q-rows; both batches.
// K (hi/lo) and V^T fragments are loaded DIRECTLY from global (L2-resident:
// 1.5 MB/head, reused by 32 blocks) — no LDS staging, no k-loop barriers.
// Swapped QK^T: S^T = mfma(K, Q) so lane li owns one q-row for softmax.
__global__ __launch_bounds__(256, 3) void attn_mfma(
    const u16t* __restrict__ Qh, const u16t* __restrict__ Ql,
    const u16t* __restrict__ Kh, const u16t* __restrict__ Kl,
    const u16t* __restrict__ Vt, const float* __restrict__ bias,
    const int* __restrict__ mask,
    u16t* __restrict__ Ah, u16t* __restrict__ Al)
{
  __shared__ u16t PL[4][16 * 72];      // per-wave P [16 qi][64 kj] bf16, padded

  const int t = threadIdx.x, lane = t & 63, wid = t >> 6;
  const int h = blockIdx.y;
  const int q0 = blockIdx.x * 64;
  const int lg = lane >> 4, li = lane & 15;
  const int qrow = q0 + wid*16 + li;          // this lane's softmax row

  s16x8 qf[2][2][2];                          // [batch][k-chunk][hi/lo]
#pragma unroll
  for (int b = 0; b < 2; ++b)
#pragma unroll
    for (int c = 0; c < 2; ++c){
      size_t o = (size_t)(b*2048 + qrow)*1024 + h*64 + c*32 + lg*8;
      qf[b][c][0] = *(const s16x8*)&Qh[o];
      qf[b][c][1] = *(const s16x8*)&Ql[o];
    }

  f32x4 Oacc[2][4];
#pragma unroll
  for (int b = 0; b < 2; ++b)
#pragma unroll
    for (int d = 0; d < 4; ++d) Oacc[b][d] = f32x4{0.f,0.f,0.f,0.f};
  float m_s[2] = {-__builtin_inff(), -__builtin_inff()};
  float l_s[2] = {0.f, 0.f};

  for (int k0 = 0; k0 < 2048; k0 += 64){
    // bias tile (batch-independent): issue early, consumed after QK^T MFMAs
    float4 bb[4];
#pragma unroll
    for (int tt = 0; tt < 4; ++tt)
      bb[tt] = *(const float4*)&bias[(size_t)(h*2048 + qrow)*2048 + k0 + tt*16 + lg*4];

#pragma unroll
    for (int b = 0; b < 2; ++b){
      // ---- S^T = K @ Q^T, split-3, fragments direct from global (L2) ----
      f32x4 sa[4];
#pragma unroll
      for (int tt = 0; tt < 4; ++tt) sa[tt] = f32x4{0.f,0.f,0.f,0.f};
#pragma unroll
      for (int tt = 0; tt < 4; ++tt)
#pragma unroll
        for (int c = 0; c < 2; ++c){
          size_t ko = (size_t)(b*2048 + k0 + tt*16 + li)*1024 + h*64 + c*32 + lg*8;
          s16x8 kh = *(const s16x8*)&Kh[ko];
          s16x8 kl = *(const s16x8*)&Kl[ko];
          sa[tt] = mfma16(kh, qf[b][c][0], sa[tt]);
          sa[tt] = mfma16(kh, qf[b][c][1], sa[tt]);
          sa[tt] = mfma16(kl, qf[b][c][0], sa[tt]);
        }

      // ---- bias + mask + online softmax (lane owns row qrow) ----
      float pv[4][4];
      float rm = -FLT_MAX;
#pragma unroll
      for (int tt = 0; tt < 4; ++tt){
        int4 mk = *(const int4*)&mask[b*2048 + k0 + tt*16 + lg*4];
        float ba[4] = {bb[tt].x, bb[tt].y, bb[tt].z, bb[tt].w};
        int ma[4] = {mk.x, mk.y, mk.z, mk.w};
#pragma unroll
        for (int r = 0; r < 4; ++r){
          float s = (ma[r] > 0) ? sa[tt][r] + ba[r] : -FLT_MAX;
          pv[tt][r] = s;
          rm = fmaxf(rm, s);
        }
      }
      rm = fmaxf(rm, __shfl_xor(rm, 16, 64));
      rm = fmaxf(rm, __shfl_xor(rm, 32, 64));
      float mo = m_s[b];
      float mn = fmaxf(mo, rm);
      float sc = __expf(mo - mn);             // -inf - finite -> 0
      float rs = 0.f;
#pragma unroll
      for (int tt = 0; tt < 4; ++tt)
#pragma unroll
        for (int r = 0; r < 4; ++r){
          float p = __expf(pv[tt][r] - mn);
          pv[tt][r] = p;
          rs += p;
        }
      rs += __shfl_xor(rs, 16, 64);
      rs += __shfl_xor(rs, 32, 64);
      m_s[b] = mn;
      l_s[b] = l_s[b]*sc + rs;

      // P -> per-wave LDS [qi][kj] (bf16); same-wave write->read, no barrier
#pragma unroll
      for (int tt = 0; tt < 4; ++tt){
        u16x4v pk;
#pragma unroll
        for (int r = 0; r < 4; ++r) pk[r] = f2bf(pv[tt][r]);
        *(u16x4v*)&PL[wid][li*72 + tt*16 + lg*4] = pk;
      }

      // rescale O (O-frag rows are qi' = lg*4+r; sc is li-indexed)
      float scb[4];
#pragma unroll
      for (int r = 0; r < 4; ++r) scb[r] = __shfl(sc, lg*4 + r, 64);
#pragma unroll
      for (int d = 0; d < 4; ++d)
#pragma unroll
        for (int r = 0; r < 4; ++r) Oacc[b][d][r] *= scb[r];

      // ---- PV: A = P from LDS, B = V^T fragments direct from global ----
      s16x8 pf[2];
#pragma unroll
      for (int c = 0; c < 2; ++c)
        pf[c] = *(const s16x8*)&PL[wid][li*72 + c*32 + lg*8];
#pragma unroll
      for (int d = 0; d < 4; ++d)
#pragma unroll
        for (int c = 0; c < 2; ++c){
          size_t vo = (size_t)(h*64 + d*16 + li)*4096 + b*2048 + k0 + c*32 + lg*8;
          s16x8 vf = *(const s16x8*)&Vt[vo];
          Oacc[b][d] = mfma16(pf[c], vf, Oacc[b][d]);
        }
    }
  }

  // epilogue: normalize, split to bf16 hi/lo, row-major [token][1024]
#pragma unroll
  for (int b = 0; b < 2; ++b){
    float inv[4];
#pragma unroll
    for (int r = 0; r < 4; ++r){
      float lr = __shfl(l_s[b], lg*4 + r, 64);
      inv[r] = 1.f / lr;
    }
#pragma unroll
    for (int d = 0; d < 4; ++d)
#pragma unroll
      for (int r = 0; r < 4; ++r){
        size_t tok = (size_t)(b*2048 + q0 + wid*16 + lg*4 + r);
        int col = h*64 + d*16 + li;
        float v = Oacc[b][d][r] * inv[r];
        u16t hh = f2bf(v);
        Ah[tok*1024 + col] = hh;
        Al[tok*1024 + col] = f2bf(v - bf2f(hh));
      }
  }
}

// -----------------------------------------------------------------------------
extern "C" void kernel_launch(void* const* d_in, const int* in_sizes, int n_in,
                              void* d_out, int out_size, void* d_ws, size_t ws_size,
                              hipStream_t stream)
{
  (void)in_sizes; (void)n_in; (void)out_size; (void)ws_size;
  const float* x    = (const float*)d_in[0];
  const int*   mask = (const int*)d_in[1];
  const float* bias = (const float*)d_in[2];
  const float* Wq   = (const float*)d_in[3];
  const float* Wk   = (const float*)d_in[4];
  const float* Wv   = (const float*)d_in[5];
  const float* Wo   = (const float*)d_in[6];
  float* out = (float*)d_out;

  uint8_t* wsb = (uint8_t*)d_ws;
  const size_t MB = (size_t)1 << 20;
  u16t* Xh   = (u16t*)(wsb +  0*MB);   // 8 MB  (reused as attn-out hi)
  u16t* Xl   = (u16t*)(wsb +  8*MB);   // 8 MB  (reused as attn-out lo)
  u16t* Wqth = (u16t*)(wsb + 16*MB);   // 2 MB each; [16,24) reused as V^T later
  u16t* Wqtl = (u16t*)(wsb + 18*MB);
  u16t* Wkth = (u16t*)(wsb + 20*MB);
  u16t* Wktl = (u16t*)(wsb + 22*MB);
  u16t* Wvth = (u16t*)(wsb + 24*MB);
  u16t* Woth = (u16t*)(wsb + 26*MB);
  u16t* Wotl = (u16t*)(wsb + 28*MB);
  u16t* Qh_  = (u16t*)(wsb + 30*MB);   // 8 MB
  u16t* Ql_  = (u16t*)(wsb + 38*MB);
  u16t* Kh_  = (u16t*)(wsb + 46*MB);
  u16t* Kl_  = (u16t*)(wsb + 54*MB);   // total 62 MB
  u16t* Vt_  = (u16t*)(wsb + 16*MB);   // V^T[1024][4096], overlays dead Wq/Wk planes
  u16t* Aath = Xh;                     // attn out hi, overlays dead Xh
  u16t* Aatl = Xl;

  prep_split<<<dim3(2048), 256, 0, stream>>>(x, Xh, Xl, 4096*1024/8);
  prep_wt<<<dim3(16,16,4), 256, 0, stream>>>(Wq, Wk, Wv, Wo,
      Wqth, Wqtl, Wkth, Wktl, Wvth, Woth, Wotl);

  // Q and K projections (split-3, bf16 hi/lo out)
  gemm_k<3,0><<<dim3(32,8,2), 256, 0, stream>>>(Xh, Xl, Wqth, Wqtl, Wkth, Wktl,
      Qh_, Ql_, Kh_, Kl_, nullptr);
  // V projection (plain bf16, transposed output V^T)
  gemm_k<1,1><<<dim3(32,8,1), 256, 0, stream>>>(Xh, nullptr, Wvth, nullptr,
      nullptr, nullptr, Vt_, nullptr, nullptr, nullptr, nullptr);

  attn_mfma<<<dim3(32,16), 256, 0, stream>>>(Qh_, Ql_, Kh_, Kl_, Vt_, bias, mask,
      Aath, Aatl);

  // output projection (split-3, fp32 out)
  gemm_k<3,2><<<dim3(32,8,1), 256, 0, stream>>>(Aath, Aatl, Woth, Wotl,
      nullptr, nullptr, nullptr, nullptr, nullptr, nullptr, out);
}

// Round 6
// 637.997 us; speedup vs baseline: 1.4522x; 1.4522x over previous
//
#include <hip/hip_runtime.h>
#include <float.h>
#include <math.h>

// B=2, L=2048, DIM=DIM_ATTN=1024, 16 heads x 64
typedef short s16x8 __attribute__((ext_vector_type(8)));
typedef float f32x4 __attribute__((ext_vector_type(4)));
typedef unsigned short u16t;
typedef u16t u16x4v __attribute__((ext_vector_type(4)));
typedef unsigned int u32;

__device__ __forceinline__ u16t f2bf(float f){
  unsigned u = __builtin_bit_cast(unsigned, f);
  return (u16t)((u + 0x7FFFu + ((u >> 16) & 1u)) >> 16);   // RNE; inputs finite
}
__device__ __forceinline__ float bf2f(u16t b){
  unsigned u = ((unsigned)b) << 16;
  return __builtin_bit_cast(float, u);
}
__device__ __forceinline__ f32x4 mfma16(s16x8 a, s16x8 b, f32x4 c){
  return __builtin_amdgcn_mfma_f32_16x16x32_bf16(a, b, c, 0, 0, 0);
}
// async global->LDS, 16B per lane; LDS dest = wave-uniform base + lane*16
__device__ __forceinline__ void gload16(const void* g, void* lds){
  __builtin_amdgcn_global_load_lds(
      (const __attribute__((address_space(1))) u32*)g,
      (__attribute__((address_space(3))) u32*)lds, 16, 0, 0);
}

// ---------------- prep: split fp32 -> bf16 hi/lo -----------------------------
__global__ __launch_bounds__(256) void prep_split(const float* __restrict__ X,
    u16t* __restrict__ H, u16t* __restrict__ L, int n8){
  int i = blockIdx.x * 256 + threadIdx.x;
  if (i >= n8) return;
  const float* p = X + (size_t)i * 8;
  float4 a = *(const float4*)p;
  float4 b = *(const float4*)(p + 4);
  float v[8] = {a.x, a.y, a.z, a.w, b.x, b.y, b.z, b.w};
  s16x8 hv, lv;
#pragma unroll
  for (int r = 0; r < 8; ++r){
    u16t hh = f2bf(v[r]);
    hv[r] = (short)hh;
    lv[r] = (short)f2bf(v[r] - bf2f(hh));
  }
  *(s16x8*)(H + (size_t)i * 8) = hv;
  *(s16x8*)(L + (size_t)i * 8) = lv;
}

// ---------------- prep: transpose weights [K][N]->[N][K] + split -------------
__global__ __launch_bounds__(256) void prep_wt(
    const float* __restrict__ Wq, const float* __restrict__ Wk,
    const float* __restrict__ Wv, const float* __restrict__ Wo,
    u16t* __restrict__ Qh, u16t* __restrict__ Ql,
    u16t* __restrict__ Kh, u16t* __restrict__ Kl,
    u16t* __restrict__ Vh,
    u16t* __restrict__ Oh, u16t* __restrict__ Ol){
  __shared__ float T[64][65];
  int z = blockIdx.z;
  const float* W = (z==0)?Wq:(z==1)?Wk:(z==2)?Wv:Wo;
  u16t* OH = (z==0)?Qh:(z==1)?Kh:(z==2)?Vh:Oh;
  u16t* OL = (z==0)?Ql:(z==1)?Kl:(z==2)?(u16t*)0:Ol;
  int k0 = blockIdx.x*64, n0 = blockIdx.y*64;
  int r = threadIdx.x >> 2, c = (threadIdx.x & 3) * 16;
#pragma unroll
  for (int i = 0; i < 4; ++i){
    float4 v = *(const float4*)&W[(size_t)(k0 + r)*1024 + n0 + c + i*4];
    T[r][c + i*4 + 0] = v.x; T[r][c + i*4 + 1] = v.y;
    T[r][c + i*4 + 2] = v.z; T[r][c + i*4 + 3] = v.w;
  }
  __syncthreads();
  s16x8 hv0, hv1, lv0, lv1;
#pragma unroll
  for (int i = 0; i < 16; ++i){
    float v = T[c + i][r];
    u16t hh = f2bf(v);
    u16t ll = f2bf(v - bf2f(hh));
    if (i < 8){ hv0[i] = (short)hh; lv0[i] = (short)ll; }
    else      { hv1[i-8] = (short)hh; lv1[i-8] = (short)ll; }
  }
  size_t o = (size_t)(n0 + r)*1024 + k0 + c;
  *(s16x8*)(OH + o)     = hv0;
  *(s16x8*)(OH + o + 8) = hv1;
  if (OL){ *(s16x8*)(OL + o) = lv0; *(s16x8*)(OL + o + 8) = lv1; }
}

// ---------------- MFMA GEMM, 64x128 tile, BK=32, dbuf + global_load_lds ------
// A row-major bf16 (hi/lo), B TRANSPOSED [N][K] bf16 (hi/lo).
// NSPLIT=3: AhBh+AhBl+AlBh. NSPLIT=1: plain bf16.
// MODE 0: bf16 hi/lo row-major out. MODE 1: bf16 V^T[n][token]. MODE 2: fp32.
template<int NSPLIT, int MODE>
__global__ __launch_bounds__(256, 3) void gemm_k(
    const u16t* __restrict__ Agh, const u16t* __restrict__ Agl,
    const u16t* __restrict__ Bgh0, const u16t* __restrict__ Bgl0,
    const u16t* __restrict__ Bgh1, const u16t* __restrict__ Bgl1,
    u16t* __restrict__ Oh0, u16t* __restrict__ Ol0,
    u16t* __restrict__ Oh1, u16t* __restrict__ Ol1,
    float* __restrict__ Of)
{
  constexpr int BUFE = (NSPLIT==3) ? 12288 : 6144;   // elems per buffer
  constexpr int AHI = 0, ALO = 2048, BHI = (NSPLIT==3)?4096:2048, BLO = 8192;
  __shared__ u16t SM[2*BUFE];                        // 48KB (split3) / 24KB

  const u16t* Bgh = blockIdx.z ? Bgh1 : Bgh0;
  const u16t* Bgl = blockIdx.z ? Bgl1 : Bgl0;
  u16t* Oh = blockIdx.z ? Oh1 : Oh0;
  u16t* Ol = blockIdx.z ? Ol1 : Ol0;

  const int t = threadIdx.x, lane = t & 63, wid = t >> 6;
  const int bm = blockIdx.x*64, bn = blockIdx.y*128;
  const int li = lane & 15, lg = lane >> 4;

  // stage one BK=32 slab: source chunk pre-swizzled (ch = sl ^ ((row>>1)&3)),
  // LDS linear; read applies the same XOR -> conflict-free ds_read_b128.
  auto stage = [&](int buf, int k0){
    u16t* B = SM + buf*BUFE;
    int lr = lane >> 2, sl = lane & 3;
    {
      int row = wid*16 + lr;
      int ch = sl ^ ((row>>1)&3);
      size_t g = (size_t)(bm+row)*1024 + k0 + ch*8;
      gload16(&Agh[g], B + AHI + wid*512);
      if constexpr (NSPLIT==3) gload16(&Agl[g], B + ALO + wid*512);
    }
#pragma unroll
    for (int c = 0; c < 2; ++c){
      int row = wid*32 + c*16 + lr;
      int ch = sl ^ ((row>>1)&3);
      size_t g = (size_t)(bn+row)*1024 + k0 + ch*8;
      gload16(&Bgh[g], B + BHI + wid*1024 + c*512);
      if constexpr (NSPLIT==3) gload16(&Bgl[g], B + BLO + wid*1024 + c*512);
    }
  };

  f32x4 acc[4][2];
#pragma unroll
  for (int i = 0; i < 4; ++i)
#pragma unroll
    for (int j = 0; j < 2; ++j) acc[i][j] = f32x4{0.f,0.f,0.f,0.f};

  stage(0, 0);
  for (int ks = 0; ks < 32; ++ks){
    __syncthreads();                       // drains stage(ks); prev compute done
    if (ks+1 < 32) stage((ks+1)&1, (ks+1)*32);   // in flight during compute
    const u16t* B = SM + (ks&1)*BUFE;
    s16x8 ah[4], alv[4], bh[2], blv[2];
#pragma unroll
    for (int i = 0; i < 4; ++i){
      int row = i*16 + li;
      int off = row*32 + (lg ^ ((row>>1)&3))*8;
      ah[i] = *(const s16x8*)&B[AHI + off];
      if constexpr (NSPLIT==3) alv[i] = *(const s16x8*)&B[ALO + off];
    }
#pragma unroll
    for (int j = 0; j < 2; ++j){
      int row = wid*32 + j*16 + li;
      int off = row*32 + (lg ^ ((row>>1)&3))*8;
      bh[j] = *(const s16x8*)&B[BHI + off];
      if constexpr (NSPLIT==3) blv[j] = *(const s16x8*)&B[BLO + off];
    }
#pragma unroll
    for (int i = 0; i < 4; ++i)
#pragma unroll
      for (int j = 0; j < 2; ++j){
        acc[i][j] = mfma16(ah[i], bh[j], acc[i][j]);
        if constexpr (NSPLIT==3){
          acc[i][j] = mfma16(ah[i], blv[j], acc[i][j]);
          acc[i][j] = mfma16(alv[i], bh[j], acc[i][j]);
        }
      }
  }

#pragma unroll
  for (int i = 0; i < 4; ++i)
#pragma unroll
    for (int j = 0; j < 2; ++j){
      if constexpr (MODE == 1){
        int n = bn + wid*32 + j*16 + li;
        int tok0 = bm + i*16 + lg*4;
        u16x4v pk;
#pragma unroll
        for (int r = 0; r < 4; ++r) pk[r] = f2bf(acc[i][j][r]);
        *(u16x4v*)&Oh[(size_t)n*4096 + tok0] = pk;
      } else {
#pragma unroll
        for (int r = 0; r < 4; ++r){
          int tok = bm + i*16 + lg*4 + r;
          int col = bn + wid*32 + j*16 + li;
          float v = acc[i][j][r];
          if constexpr (MODE == 0){
            u16t hh = f2bf(v);
            Oh[(size_t)tok*1024 + col] = hh;
            Ol[(size_t)tok*1024 + col] = f2bf(v - bf2f(hh));
          } else {
            Of[(size_t)tok*1024 + col] = v;
          }
        }
      }
    }
}

// ---------------- MFMA flash attention, double-buffered K staging ------------
// Block = (64-q-tile, head), 4 waves; steps = (k-tile, batch), K hi/lo staged
// via global_load_lds (dbuf, 1 barrier/step); V^T + bias + mask prefetched to
// registers at step start. Swapped QK^T; split-3 QK^T, plain-bf16 PV.
__global__ __launch_bounds__(256, 2) void attn_mfma(
    const u16t* __restrict__ Qh, const u16t* __restrict__ Ql,
    const u16t* __restrict__ Kh, const u16t* __restrict__ Kl,
    const u16t* __restrict__ Vt, const float* __restrict__ bias,
    const int* __restrict__ mask,
    u16t* __restrict__ Ah, u16t* __restrict__ Al)
{
  __shared__ u16t KB[2][2][4096];      // [buf][hi/lo][64 rows][64 elems] 32KB
  __shared__ u16t PL[4][16*72];        // per-wave P [qi][kj] bf16, 9KB

  const int t = threadIdx.x, lane = t & 63, wid = t >> 6;
  const int h = blockIdx.y, q0 = blockIdx.x*64;
  const int lg = lane >> 4, li = lane & 15;
  const int qrow = q0 + wid*16 + li;

  s16x8 qf[2][2][2];                   // [batch][k-chunk][hi/lo]
#pragma unroll
  for (int b = 0; b < 2; ++b)
#pragma unroll
    for (int c = 0; c < 2; ++c){
      size_t o = (size_t)(b*2048 + qrow)*1024 + h*64 + c*32 + lg*8;
      qf[b][c][0] = *(const s16x8*)&Qh[o];
      qf[b][c][1] = *(const s16x8*)&Ql[o];
    }

  f32x4 Oacc[2][4];
#pragma unroll
  for (int b = 0; b < 2; ++b)
#pragma unroll
    for (int d = 0; d < 4; ++d) Oacc[b][d] = f32x4{0.f,0.f,0.f,0.f};
  float m_s[2] = {-__builtin_inff(), -__builtin_inff()};
  float l_s[2] = {0.f, 0.f};
  float4 bb[4];                        // bias tile, persists across b=0 -> b=1

  auto stageK = [&](int buf, int b, int k0){
    int lr = lane >> 3, sl = lane & 7;
#pragma unroll
    for (int c = 0; c < 2; ++c){
      int row = wid*16 + c*8 + lr;
      int ch = sl ^ (row & 7);         // pre-swizzled source; read re-applies XOR
      size_t g = (size_t)(b*2048 + k0 + row)*1024 + h*64 + ch*8;
      gload16(&Kh[g], &KB[buf][0][(wid*16 + c*8)*64]);
      gload16(&Kl[g], &KB[buf][1][(wid*16 + c*8)*64]);
    }
  };

  auto compute = [&](int b, int buf, int k0, bool ldbias,
                     f32x4 (&Oac)[4], float& m_r, float& l_r,
                     s16x8 (&qfb)[2][2]){
    // prefetch V^T fragments (consumed after QK^T+softmax, ~1000cyc slack)
    s16x8 vf[4][2];
#pragma unroll
    for (int d = 0; d < 4; ++d)
#pragma unroll
      for (int c = 0; c < 2; ++c)
        vf[d][c] = *(const s16x8*)&Vt[(size_t)(h*64 + d*16 + li)*4096
                                      + b*2048 + k0 + c*32 + lg*8];
    if (ldbias){
#pragma unroll
      for (int tt = 0; tt < 4; ++tt)
        bb[tt] = *(const float4*)&bias[(size_t)(h*2048 + qrow)*2048
                                       + k0 + tt*16 + lg*4];
    }
    int4 mk[4];
#pragma unroll
    for (int tt = 0; tt < 4; ++tt)
      mk[tt] = *(const int4*)&mask[b*2048 + k0 + tt*16 + lg*4];

    // S^T = K @ Q^T (split-3)
    f32x4 sa[4];
#pragma unroll
    for (int tt = 0; tt < 4; ++tt) sa[tt] = f32x4{0.f,0.f,0.f,0.f};
#pragma unroll
    for (int tt = 0; tt < 4; ++tt)
#pragma unroll
      for (int c = 0; c < 2; ++c){
        int row = tt*16 + li;
        int off = row*64 + (((c*4 + lg) ^ (row & 7))*8);
        s16x8 kh = *(const s16x8*)&KB[buf][0][off];
        s16x8 kl = *(const s16x8*)&KB[buf][1][off];
        sa[tt] = mfma16(kh, qfb[c][0], sa[tt]);
        sa[tt] = mfma16(kh, qfb[c][1], sa[tt]);
        sa[tt] = mfma16(kl, qfb[c][0], sa[tt]);
      }

    // bias + mask + online softmax (lane owns q-row qrow)
    float pv[4][4];
    float rm = -FLT_MAX;
#pragma unroll
    for (int tt = 0; tt < 4; ++tt){
      float ba[4] = {bb[tt].x, bb[tt].y, bb[tt].z, bb[tt].w};
      int ma[4] = {mk[tt].x, mk[tt].y, mk[tt].z, mk[tt].w};
#pragma unroll
      for (int r = 0; r < 4; ++r){
        float s = (ma[r] > 0) ? sa[tt][r] + ba[r] : -FLT_MAX;
        pv[tt][r] = s;
        rm = fmaxf(rm, s);
      }
    }
    rm = fmaxf(rm, __shfl_xor(rm, 16, 64));
    rm = fmaxf(rm, __shfl_xor(rm, 32, 64));
    float mo = m_r;
    float mn = fmaxf(mo, rm);
    float sc = __expf(mo - mn);
    float rs = 0.f;
#pragma unroll
    for (int tt = 0; tt < 4; ++tt)
#pragma unroll
      for (int r = 0; r < 4; ++r){
        float p = __expf(pv[tt][r] - mn);
        pv[tt][r] = p;
        rs += p;
      }
    rs += __shfl_xor(rs, 16, 64);
    rs += __shfl_xor(rs, 32, 64);
    m_r = mn;
    l_r = l_r*sc + rs;

    // P -> per-wave LDS (same-wave write->read)
#pragma unroll
    for (int tt = 0; tt < 4; ++tt){
      u16x4v pk;
#pragma unroll
      for (int r = 0; r < 4; ++r) pk[r] = f2bf(pv[tt][r]);
      *(u16x4v*)&PL[wid][li*72 + tt*16 + lg*4] = pk;
    }
    float scb[4];
#pragma unroll
    for (int r = 0; r < 4; ++r) scb[r] = __shfl(sc, lg*4 + r, 64);
#pragma unroll
    for (int d = 0; d < 4; ++d)
#pragma unroll
      for (int r = 0; r < 4; ++r) Oac[d][r] *= scb[r];

    s16x8 pf[2];
#pragma unroll
    for (int c = 0; c < 2; ++c)
      pf[c] = *(const s16x8*)&PL[wid][li*72 + c*32 + lg*8];
#pragma unroll
    for (int d = 0; d < 4; ++d)
#pragma unroll
      for (int c = 0; c < 2; ++c)
        Oac[d] = mfma16(pf[c], vf[d][c], Oac[d]);
  };

  stageK(0, 0, 0);                     // prologue: buf0 <- (b0, kt0)
  for (int kt = 0; kt < 32; ++kt){
    int k0 = kt*64;
    __syncthreads();                   // buf0 ready; prev b1-compute done
    stageK(1, 1, k0);                  // buf1 <- (b1,kt), overlaps b0 compute
    compute(0, 0, k0, true,  Oacc[0], m_s[0], l_s[0], qf[0]);
    __syncthreads();                   // buf1 ready; b0-compute done
    if (kt+1 < 32) stageK(0, 0, k0+64);// buf0 <- (b0,kt+1), overlaps b1 compute
    compute(1, 1, k0, false, Oacc[1], m_s[1], l_s[1], qf[1]);
  }

  // epilogue: normalize, split to bf16 hi/lo, row-major [token][1024]
#pragma unroll
  for (int b = 0; b < 2; ++b){
    float inv[4];
#pragma unroll
    for (int r = 0; r < 4; ++r){
      float lr = __shfl(l_s[b], lg*4 + r, 64);
      inv[r] = 1.f / lr;
    }
#pragma unroll
    for (int d = 0; d < 4; ++d)
#pragma unroll
      for (int r = 0; r < 4; ++r){
        size_t tok = (size_t)(b*2048 + q0 + wid*16 + lg*4 + r);
        int col = h*64 + d*16 + li;
        float v = Oacc[b][d][r] * inv[r];
        u16t hh = f2bf(v);
        Ah[tok*1024 + col] = hh;
        Al[tok*1024 + col] = f2bf(v - bf2f(hh));
      }
  }
}

// -----------------------------------------------------------------------------
extern "C" void kernel_launch(void* const* d_in, const int* in_sizes, int n_in,
                              void* d_out, int out_size, void* d_ws, size_t ws_size,
                              hipStream_t stream)
{
  (void)in_sizes; (void)n_in; (void)out_size; (void)ws_size;
  const float* x    = (const float*)d_in[0];
  const int*   mask = (const int*)d_in[1];
  const float* bias = (const float*)d_in[2];
  const float* Wq   = (const float*)d_in[3];
  const float* Wk   = (const float*)d_in[4];
  const float* Wv   = (const float*)d_in[5];
  const float* Wo   = (const float*)d_in[6];
  float* out = (float*)d_out;

  uint8_t* wsb = (uint8_t*)d_ws;
  const size_t MB = (size_t)1 << 20;
  u16t* Xh   = (u16t*)(wsb +  0*MB);   // 8 MB (reused as attn-out hi)
  u16t* Xl   = (u16t*)(wsb +  8*MB);   // 8 MB (reused as attn-out lo)
  u16t* Wqth = (u16t*)(wsb + 16*MB);   // 2 MB each; [16,24) reused as V^T later
  u16t* Wqtl = (u16t*)(wsb + 18*MB);
  u16t* Wkth = (u16t*)(wsb + 20*MB);
  u16t* Wktl = (u16t*)(wsb + 22*MB);
  u16t* Wvth = (u16t*)(wsb + 24*MB);
  u16t* Woth = (u16t*)(wsb + 26*MB);
  u16t* Wotl = (u16t*)(wsb + 28*MB);
  u16t* Qh_  = (u16t*)(wsb + 30*MB);   // 8 MB
  u16t* Ql_  = (u16t*)(wsb + 38*MB);
  u16t* Kh_  = (u16t*)(wsb + 46*MB);
  u16t* Kl_  = (u16t*)(wsb + 54*MB);
  u16t* Vt_  = (u16t*)(wsb + 16*MB);   // V^T[1024][4096] overlays dead Wq/Wk
  u16t* Aath = Xh;
  u16t* Aatl = Xl;

  prep_split<<<dim3(2048), 256, 0, stream>>>(x, Xh, Xl, 4096*1024/8);
  prep_wt<<<dim3(16,16,4), 256, 0, stream>>>(Wq, Wk, Wv, Wo,
      Wqth, Wqtl, Wkth, Wktl, Wvth, Woth, Wotl);

  // Q and K projections (split-3, bf16 hi/lo out)
  gemm_k<3,0><<<dim3(64,8,2), 256, 0, stream>>>(Xh, Xl, Wqth, Wqtl, Wkth, Wktl,
      Qh_, Ql_, Kh_, Kl_, nullptr);
  // V projection (plain bf16, transposed output V^T)
  gemm_k<1,1><<<dim3(64,8,1), 256, 0, stream>>>(Xh, nullptr, Wvth, nullptr,
      nullptr, nullptr, Vt_, nullptr, nullptr, nullptr, nullptr);

  attn_mfma<<<dim3(32,16), 256, 0, stream>>>(Qh_, Ql_, Kh_, Kl_, Vt_, bias, mask,
      Aath, Aatl);

  // output projection (split-3, fp32 out)
  gemm_k<3,2><<<dim3(64,8,1), 256, 0, stream>>>(Aath, Aatl, Woth, Wotl,
      nullptr, nullptr, nullptr, nullptr, nullptr, nullptr, out);
}